// Round 1
// baseline (367.766 us; speedup 1.0000x reference)
//
#include <hip/hip_runtime.h>
#include <hip/hip_bf16.h>
#include <math.h>

#define NN  128   // total nodes
#define BS  128   // samples per block == threads (main & pilot)
#define GRP 16    // z prefetch group size

struct NodeP {
    float w0, w1, bb, sigma;
    int   p0, p1, root, pad;
};

// ws layout:
//   [0,    4096)   NodeP params[128]
//   [4096, 5120)   const float* srcs[128]
//   [8192, +128K)  pilot vals [128][256]

__global__ __launch_bounds__(128) void prep_kernel(
    const float* __restrict__ W, const float* __restrict__ b,
    const float* __restrict__ pm, const int* __restrict__ pidx,
    const float* __restrict__ root_main, const float* __restrict__ z,
    size_t NS, NodeP* __restrict__ params, const float** __restrict__ srcs)
{
    int i = threadIdx.x;
    if (i < NN) {
        float m0 = pm[2 * i], m1 = pm[2 * i + 1];
        NodeP p;
        p.w0 = W[2 * i] * m0;
        p.w1 = W[2 * i + 1] * m1;
        p.bb = b[i];
        p.sigma = 0.0f;                 // filled in by quant_kernel
        p.p0 = pidx[2 * i];
        p.p1 = pidx[2 * i + 1];
        p.root = (m0 + m1 == 0.0f) ? 1 : 0;   // root <=> no parents
        p.pad = 0;
        params[i] = p;
        srcs[i] = (p.root ? root_main : z) + (size_t)i * NS;
    }
}

// Noiseless pilot pass: 2 blocks x 128 samples, writes pilot vals [node][CAL]
__global__ __launch_bounds__(128) void pilot_kernel(
    const NodeP* __restrict__ params, const float* __restrict__ root_pilot,
    float* __restrict__ pilot_out, int CAL)
{
    __shared__ float vals[NN * BS];
    const int tid = threadIdx.x;
    const int j = blockIdx.x * BS + tid;
    for (int i = 0; i < NN; ++i) {
        NodeP p = params[i];
        float v;
        if (p.root) {
            v = root_pilot[(size_t)i * CAL + j];
        } else {
            float a = vals[p.p0 * BS + (tid ^ (p.p0 & 31))];
            float c = vals[p.p1 * BS + (tid ^ (p.p1 & 31))];
            v = fmaxf(fmaf(p.w0, a, fmaf(p.w1, c, p.bb)), 0.0f);
        }
        if (!isfinite(v)) v = 0.0f;
        vals[i * BS + (tid ^ (i & 31))] = v;
        pilot_out[(size_t)i * CAL + j] = v;
    }
}

// Per-node quantiles via bitonic sort of CAL=256 values; sigma into params.
__global__ __launch_bounds__(256) void quant_kernel(
    const float* __restrict__ pilot, NodeP* __restrict__ params, int CAL)
{
    __shared__ float s[256];
    const int tid = threadIdx.x;
    const int node = blockIdx.x;
    s[tid] = pilot[(size_t)node * CAL + tid];
    __syncthreads();
    for (int k = 2; k <= 256; k <<= 1) {
        for (int jj = k >> 1; jj > 0; jj >>= 1) {
            int ixj = tid ^ jj;
            if (ixj > tid) {
                float a = s[tid], bv = s[ixj];
                bool up = ((tid & k) == 0);
                if ((a > bv) == up) { s[tid] = bv; s[ixj] = a; }
            }
            __syncthreads();
        }
    }
    if (tid == 0) {
        // jnp.quantile linear interp: pos = q*(n-1); n=256
        float q25 = s[63]  + 0.75f * (s[64]  - s[63]);
        float q75 = s[191] + 0.25f * (s[192] - s[191]);
        params[node].sigma = 0.1f * fmaxf(q75 - q25, 1e-6f);
    }
}

// Main pass: one block = 128 samples; vals kept in XOR-swizzled LDS.
// Element (node n, local sample t) lives at n*BS + (t ^ (n & 31)):
//   compute phase (n uniform, t = lane)      -> banks = permutation of lanes, conflict-free
//   epilogue    (t uniform-ish, n = chosen)  -> banks spread by n&31, ~2-way (free)
__global__ __launch_bounds__(128) void main_kernel(
    const NodeP* __restrict__ params, const float* const* __restrict__ srcs,
    const int* __restrict__ chosen, float* __restrict__ out, size_t NS)
{
    __shared__ float vals[NN * BS];   // 64 KB
    const int tid = threadIdx.x;
    const size_t j = (size_t)blockIdx.x * BS + tid;

    float zb[2][GRP];
    #pragma unroll
    for (int u = 0; u < GRP; ++u) zb[0][u] = srcs[u][j];

    #pragma unroll
    for (int g = 0; g < NN / GRP; ++g) {
        if (g + 1 < NN / GRP) {
            #pragma unroll
            for (int u = 0; u < GRP; ++u)
                zb[(g + 1) & 1][u] = srcs[(g + 1) * GRP + u][j];
        }
        #pragma unroll
        for (int u = 0; u < GRP; ++u) {
            int i = g * GRP + u;
            NodeP p = params[i];
            float zv = zb[g & 1][u];
            float v;
            if (p.root) {
                v = zv;   // src row is root_main for root nodes
            } else {
                float a = vals[p.p0 * BS + (tid ^ (p.p0 & 31))];
                float c = vals[p.p1 * BS + (tid ^ (p.p1 & 31))];
                v = fmaxf(fmaf(p.w0, a, fmaf(p.w1, c, p.bb)), 0.0f) + p.sigma * zv;
            }
            if (!isfinite(v)) v = 0.0f;
            vals[i * BS + (tid ^ (i & 31))] = v;
        }
    }

    __syncthreads();   // epilogue reads other threads' sample columns

    // out[sample][k], k over 64 chosen nodes; float4 stores, coalesced.
    float4* out4 = (float4*)(out + (size_t)blockIdx.x * BS * 64);
    #pragma unroll
    for (int it = 0; it < 16; ++it) {
        int c  = it * BS + tid;        // float4 chunk id within block, 0..2047
        int s  = c >> 4;               // local sample index
        int k0 = (c & 15) << 2;        // first chosen index of this chunk
        int n0 = chosen[k0 + 0], n1 = chosen[k0 + 1];
        int n2 = chosen[k0 + 2], n3 = chosen[k0 + 3];
        float4 o;
        o.x = vals[n0 * BS + (s ^ (n0 & 31))];
        o.y = vals[n1 * BS + (s ^ (n1 & 31))];
        o.z = vals[n2 * BS + (s ^ (n2 & 31))];
        o.w = vals[n3 * BS + (s ^ (n3 & 31))];
        out4[c] = o;
    }
}

extern "C" void kernel_launch(void* const* d_in, const int* in_sizes, int n_in,
                              void* d_out, int out_size, void* d_ws, size_t ws_size,
                              hipStream_t stream) {
    // setup_inputs order:
    // 0 n_samples(1) 1 W(256) 2 b(128) 3 root_pilot(128*256) 4 root_main(128*NS)
    // 5 z_noise(128*NS) 6 par_mask(256) 7 par_idx(256) 8 is_root(128,bool) 9 chosen(64)
    const float* W          = (const float*)d_in[1];
    const float* b          = (const float*)d_in[2];
    const float* root_pilot = (const float*)d_in[3];
    const float* root_main  = (const float*)d_in[4];
    const float* z          = (const float*)d_in[5];
    const float* pm         = (const float*)d_in[6];
    const int*   pidx       = (const int*)d_in[7];
    const int*   chosen     = (const int*)d_in[9];
    float* out = (float*)d_out;

    const size_t NS  = (size_t)in_sizes[4] / NN;   // 262144
    const int    CAL = in_sizes[3] / NN;           // 256

    char* ws = (char*)d_ws;
    NodeP*        params = (NodeP*)ws;
    const float** srcs   = (const float**)(ws + 4096);
    float*        pilot  = (float*)(ws + 8192);

    prep_kernel<<<1, 128, 0, stream>>>(W, b, pm, pidx, root_main, z, NS, params, srcs);
    pilot_kernel<<<CAL / BS, BS, 0, stream>>>(params, root_pilot, pilot, CAL);
    quant_kernel<<<NN, 256, 0, stream>>>(pilot, params, CAL);
    main_kernel<<<(int)(NS / BS), BS, 0, stream>>>(params, srcs, chosen, out, NS);
}